// Round 1
// baseline (300.700 us; speedup 1.0000x reference)
//
#include <hip/hip_runtime.h>
#include <hip/hip_fp16.h>

#define DIM 64
#define NG  16          // num graphs
#define CPG 8           // edge chunks per graph (hist)
#define NPG 4096        // nodes per graph
#define LSTR 68
#define HISTB (NG*CPG)  // 128 hist blocks
#define GGN 32          // dst nodes per fused gather+gemm block

// ---------------------------------------------------------------------------
// K1: fused. Blocks [0,HISTB): per-chunk LDS degree histograms (as before).
// Blocks [HISTB, HISTB+N/32): h16 = fp16(x @ W1)  -- NO ns scaling (deferred
// to the gather as a per-edge multiply), which breaks the dependency on the
// histogram and lets both run in one dispatch.
// ---------------------------------------------------------------------------
__global__ __launch_bounds__(256) void k1_hist_gemm(
    const int* __restrict__ src, const int* __restrict__ dst,
    int* __restrict__ hsub, int* __restrict__ dsub, int chunk, int npg,
    const float* __restrict__ x, const float* __restrict__ W1,
    __half* __restrict__ hout, int swiz)
{
    __shared__ int smem[8192];      // 32 KB union: hist(32KB) / gemm(26KB)
    const int tid = threadIdx.x;
    if ((int)blockIdx.x < HISTB) {
        int* hs = smem;
        int* hd = smem + NPG;
        const int blk = blockIdx.x;
        const int g = blk / CPG;
        const int ebase = blk * chunk;
        const int nbase = g * npg;
        for (int i = tid; i < npg; i += 256) { hs[i] = 0; hd[i] = 0; }
        __syncthreads();
        for (int e = tid; e < chunk; e += 256) {
            atomicAdd(&hs[src[ebase + e] - nbase], 1);
            atomicAdd(&hd[dst[ebase + e] - nbase], 1);
        }
        __syncthreads();
        for (int i = tid; i < npg; i += 256) {
            hsub[blk * npg + i] = hs[i];
            dsub[blk * npg + i] = hd[i];
        }
    } else {
        float* Wt = (float*)smem;            // Wt[c][k], 64*LSTR
        float* xs = Wt + 64 * LSTR;          // xs[r][k], 32*LSTR
        int blk = blockIdx.x - HISTB;
        if (swiz) {                          // 2048 blocks: 16 graphs x 128
            int xg = blk & 7;
            int j = blk >> 3;
            int g = xg + ((j >> 7) << 3);
            blk = (g << 7) + (j & 127);
        }
        const int row0 = blk * 32;
        for (int i = tid; i < 64 * 64; i += 256) {
            int k = i >> 6, c = i & 63;
            Wt[c * LSTR + k] = W1[i];
        }
        for (int i = tid; i < 32 * 64; i += 256) {
            int r = i >> 6, c = i & 63;
            xs[r * LSTR + c] = x[(size_t)(row0 + r) * 64 + c];
        }
        __syncthreads();
        const int c0 = tid & 31;
        const int r0 = tid >> 5;
        float acc[4][2] = {};
#pragma unroll
        for (int k = 0; k < 64; k += 4) {
            float4 w0 = *(const float4*)&Wt[(c0     ) * LSTR + k];
            float4 w1 = *(const float4*)&Wt[(c0 + 32) * LSTR + k];
#pragma unroll
            for (int rr = 0; rr < 4; ++rr) {
                float4 xv = *(const float4*)&xs[(r0 + 8 * rr) * LSTR + k];
                acc[rr][0] += xv.x * w0.x + xv.y * w0.y + xv.z * w0.z + xv.w * w0.w;
                acc[rr][1] += xv.x * w1.x + xv.y * w1.y + xv.z * w1.z + xv.w * w1.w;
            }
        }
#pragma unroll
        for (int rr = 0; rr < 4; ++rr) {
            int row = row0 + r0 + 8 * rr;
            hout[(size_t)row * 64 + c0     ] = __float2half_rn(acc[rr][0]);
            hout[(size_t)row * 64 + c0 + 32] = __float2half_rn(acc[rr][1]);
        }
    }
}

// ---------------------------------------------------------------------------
// K2: one block per graph. Coalesced sum of sub-hists -> ns/nd; shuffle-based
// per-graph exclusive scan of in-degrees -> rowptr; cursor = copy of rowptr
// (consumed by K3's global atomics). No dsub rewrite (sort need not be stable:
// segment-sum is order-invariant).
// ---------------------------------------------------------------------------
__global__ __launch_bounds__(1024) void k2_scan(
    const int* __restrict__ hsub, const int* __restrict__ dsub,
    float* __restrict__ ns, float* __restrict__ nd,
    int* __restrict__ rowptr, int* __restrict__ cursor,
    int epg, int npg, int N, int E)
{
    __shared__ int ddeg[NPG];       // 16 KB
    __shared__ int wsum[16];
    const int g = blockIdx.x;
    const int t = threadIdx.x;
    const int nbase = g * npg;
    const int ebase = g * epg;
    // Phase A: fully coalesced sweep (i = t + r*1024)
    for (int i = t; i < npg; i += 1024) {
        int sd = 0, dd = 0;
#pragma unroll
        for (int k = 0; k < CPG; ++k) {
            sd += hsub[(g * CPG + k) * npg + i];
            dd += dsub[(g * CPG + k) * npg + i];
        }
        ns[nbase + i] = sd > 0 ? rsqrtf((float)sd) : 0.0f;
        nd[nbase + i] = dd > 0 ? rsqrtf((float)dd) : 0.0f;
        ddeg[i] = dd;
    }
    __syncthreads();
    // Phase B: thread t owns rows 4t..4t+3; shuffle scan over 1024 threads
    const int i0 = 4 * t;
    int d0 = ddeg[i0], d1 = ddeg[i0 + 1], d2 = ddeg[i0 + 2], d3 = ddeg[i0 + 3];
    int s4 = d0 + d1 + d2 + d3;
    const int lane = t & 63, wid = t >> 6;
    int v = s4;
#pragma unroll
    for (int off = 1; off < 64; off <<= 1) {
        int u = __shfl_up(v, off, 64);
        if (lane >= off) v += u;
    }
    if (lane == 63) wsum[wid] = v;
    __syncthreads();
    if (t < 16) {
        int w = wsum[t];
#pragma unroll
        for (int off = 1; off < 16; off <<= 1) {
            int u = __shfl_up(w, off, 16);
            if (t >= off) w += u;
        }
        wsum[t] = w;    // inclusive wave sums
    }
    __syncthreads();
    int incl = v + (wid > 0 ? wsum[wid - 1] : 0);
    int c = ebase + incl - s4;      // exclusive prefix for row i0
    rowptr[nbase + i0    ] = c; cursor[nbase + i0    ] = c; c += d0;
    rowptr[nbase + i0 + 1] = c; cursor[nbase + i0 + 1] = c; c += d1;
    rowptr[nbase + i0 + 2] = c; cursor[nbase + i0 + 2] = c; c += d2;
    rowptr[nbase + i0 + 3] = c; cursor[nbase + i0 + 3] = c;
    if (g == 0 && t == 0) rowptr[N] = E;
}

// ---------------------------------------------------------------------------
// K3: fill ssrc via global-atomic cursors (unstable counting sort — fine).
// 256 blocks, no LDS, no dsub reads.
// ---------------------------------------------------------------------------
__global__ __launch_bounds__(256) void k3_fill(
    const int* __restrict__ src, const int* __restrict__ dst,
    int* __restrict__ cursor, int* __restrict__ ssrc, int chunk)
{
    const int base = blockIdx.x * chunk;
    for (int e = threadIdx.x; e < chunk; e += 256) {
        int s = src[base + e];
        int d = dst[base + e];
        int pos = atomicAdd(&cursor[d], 1);
        ssrc[pos] = s;
    }
}

// ---------------------------------------------------------------------------
// Fused gather + next-layer GEMM. Per dst node w:
//   acc = sum_{e in(w)} [ns[s] *] h[s]      (nsfold only for layer-1 output)
//   u   = acc * (nd[w]*ns[w]) + ns[w]*bprev  (prev epilogue + next pre-scale)
//   y   = u @ W ;  hout[w] = fp16(y)
// Block: 4 waves x 8 nodes = 32 nodes. W staged in LDS once per block.
// Eliminates the fp32 agg round-trip entirely.
// ---------------------------------------------------------------------------
__device__ __forceinline__ void acc_h4(float4& acc, uint2 u)
{
    __half2 p = *(__half2*)&u.x;
    __half2 q = *(__half2*)&u.y;
    float2 f0 = __half22float2(p);
    float2 f1 = __half22float2(q);
    acc.x += f0.x; acc.y += f0.y; acc.z += f1.x; acc.w += f1.y;
}

__device__ __forceinline__ void acc_h4s(float4& acc, uint2 u, float s)
{
    __half2 p = *(__half2*)&u.x;
    __half2 q = *(__half2*)&u.y;
    float2 f0 = __half22float2(p);
    float2 f1 = __half22float2(q);
    acc.x += s * f0.x; acc.y += s * f0.y; acc.z += s * f1.x; acc.w += s * f1.y;
}

__global__ __launch_bounds__(256) void gg_kernel(
    const __half* __restrict__ h, const int* __restrict__ ssrc,
    const int* __restrict__ rowptr, const float* __restrict__ ns,
    const float* __restrict__ nd, const float* __restrict__ bprev,
    const float* __restrict__ W, __half* __restrict__ hout,
    int N, int nsfold, int swiz)
{
    __shared__ float Ws[64 * 64];        // W[k][c] row-major, 16 KB
    __shared__ float us[GGN][64];        // scaled agg rows, 8 KB
    int blk = blockIdx.x;
    if (swiz) {                          // 2048 blocks: 16 graphs x 128
        int xg = blk & 7;
        int j = blk >> 3;
        int g = xg + ((j >> 7) << 3);
        blk = (g << 7) + (j & 127);
    }
    const int tid = threadIdx.x;
    for (int i = tid; i < 64 * 64; i += 256) Ws[i] = W[i];

    const int wv = tid >> 6;
    const int lane = tid & 63;
    const int grp = lane >> 4;
    const int sub = lane & 15;
    const int node0 = blk * GGN + wv * 8;

    for (int n = 0; n < 8; ++n) {
        int w = node0 + n;
        if (w >= N) break;
        int beg = rowptr[w], end = rowptr[w + 1];
        float4 acc = {0.f, 0.f, 0.f, 0.f};
        int j = beg + grp;
        if (nsfold) {
            for (; j + 12 < end; j += 16) {
                int s0 = ssrc[j];
                int s1 = ssrc[j + 4];
                int s2 = ssrc[j + 8];
                int s3 = ssrc[j + 12];
                float n0 = ns[s0], n1 = ns[s1], n2 = ns[s2], n3 = ns[s3];
                uint2 u0 = *(const uint2*)(h + (size_t)s0 * 64 + sub * 4);
                uint2 u1 = *(const uint2*)(h + (size_t)s1 * 64 + sub * 4);
                uint2 u2 = *(const uint2*)(h + (size_t)s2 * 64 + sub * 4);
                uint2 u3 = *(const uint2*)(h + (size_t)s3 * 64 + sub * 4);
                acc_h4s(acc, u0, n0); acc_h4s(acc, u1, n1);
                acc_h4s(acc, u2, n2); acc_h4s(acc, u3, n3);
            }
            for (; j < end; j += 4) {
                int s = ssrc[j];
                float nn = ns[s];
                uint2 u = *(const uint2*)(h + (size_t)s * 64 + sub * 4);
                acc_h4s(acc, u, nn);
            }
        } else {
            for (; j + 12 < end; j += 16) {
                int s0 = ssrc[j];
                int s1 = ssrc[j + 4];
                int s2 = ssrc[j + 8];
                int s3 = ssrc[j + 12];
                uint2 u0 = *(const uint2*)(h + (size_t)s0 * 64 + sub * 4);
                uint2 u1 = *(const uint2*)(h + (size_t)s1 * 64 + sub * 4);
                uint2 u2 = *(const uint2*)(h + (size_t)s2 * 64 + sub * 4);
                uint2 u3 = *(const uint2*)(h + (size_t)s3 * 64 + sub * 4);
                acc_h4(acc, u0); acc_h4(acc, u1); acc_h4(acc, u2); acc_h4(acc, u3);
            }
            for (; j < end; j += 4) {
                int s = ssrc[j];
                uint2 u = *(const uint2*)(h + (size_t)s * 64 + sub * 4);
                acc_h4(acc, u);
            }
        }
#pragma unroll
        for (int off = 32; off >= 16; off >>= 1) {
            acc.x += __shfl_down(acc.x, off, 64);
            acc.y += __shfl_down(acc.y, off, 64);
            acc.z += __shfl_down(acc.z, off, 64);
            acc.w += __shfl_down(acc.w, off, 64);
        }
        if (lane < 16) {
            float sw = ns[w];
            float alpha = nd[w] * sw;
            float4 bv = *(const float4*)(bprev + lane * 4);
            float4 uo;
            uo.x = acc.x * alpha + sw * bv.x;
            uo.y = acc.y * alpha + sw * bv.y;
            uo.z = acc.z * alpha + sw * bv.z;
            uo.w = acc.w * alpha + sw * bv.w;
            *(float4*)&us[wv * 8 + n][lane * 4] = uo;
        }
    }
    __syncthreads();
    // Epilogue GEMM: thread -> (node nl, col c). us read is wave-uniform
    // (broadcast); Ws[k*64+c] is stride-1 across lanes (2-way alias, free).
    const int c = tid & 63;
#pragma unroll
    for (int m = 0; m < 8; ++m) {
        int nl = (tid >> 6) + 4 * m;
        int w = blk * GGN + nl;
        if (w >= N) continue;
        const float* ur = us[nl];
        float y = 0.f;
#pragma unroll
        for (int k = 0; k < 64; k += 4) {
            float4 uv = *(const float4*)&ur[k];
            y += uv.x * Ws[(k    ) * 64 + c]
               + uv.y * Ws[(k + 1) * 64 + c]
               + uv.z * Ws[(k + 2) * 64 + c]
               + uv.w * Ws[(k + 3) * 64 + c];
        }
        hout[(size_t)w * 64 + c] = __float2half_rn(y);
    }
}

// ---------------------------------------------------------------------------
// Final gather (layer 3): acc*nd + b3 -> fp32 out. Unchanged structure.
// ---------------------------------------------------------------------------
__global__ __launch_bounds__(256) void gather_kernel(
    const __half* __restrict__ h, const int* __restrict__ ssrc,
    const int* __restrict__ rowptr, float* __restrict__ out,
    const float* __restrict__ nd, const float* __restrict__ b,
    int N, int swiz)
{
    int blk = blockIdx.x;
    if (swiz) {                        // 16384 blocks: 16 graphs x 1024
        int x = blk & 7;
        int j = blk >> 3;
        int g = x + ((j >> 10) << 3);
        blk = (g << 10) + (j & 1023);
    }
    int wid  = blk * 4 + (threadIdx.x >> 6);
    int lane = threadIdx.x & 63;
    if (wid >= N) return;
    int beg = rowptr[wid], end = rowptr[wid + 1];
    int grp = lane >> 4;
    int sub = lane & 15;
    float4 acc = {0.f, 0.f, 0.f, 0.f};
    int j = beg + grp;
    for (; j + 12 < end; j += 16) {
        int s0 = ssrc[j];
        int s1 = ssrc[j + 4];
        int s2 = ssrc[j + 8];
        int s3 = ssrc[j + 12];
        uint2 u0 = *(const uint2*)(h + (size_t)s0 * 64 + sub * 4);
        uint2 u1 = *(const uint2*)(h + (size_t)s1 * 64 + sub * 4);
        uint2 u2 = *(const uint2*)(h + (size_t)s2 * 64 + sub * 4);
        uint2 u3 = *(const uint2*)(h + (size_t)s3 * 64 + sub * 4);
        acc_h4(acc, u0); acc_h4(acc, u1); acc_h4(acc, u2); acc_h4(acc, u3);
    }
    for (; j < end; j += 4) {
        int s = ssrc[j];
        uint2 u = *(const uint2*)(h + (size_t)s * 64 + sub * 4);
        acc_h4(acc, u);
    }
#pragma unroll
    for (int off = 32; off >= 16; off >>= 1) {
        acc.x += __shfl_down(acc.x, off, 64);
        acc.y += __shfl_down(acc.y, off, 64);
        acc.z += __shfl_down(acc.z, off, 64);
        acc.w += __shfl_down(acc.w, off, 64);
    }
    if (lane < 16) {
        float n = nd[wid];
        const float4 bv = *(const float4*)(b + lane * 4);
        acc.x = acc.x * n + bv.x;
        acc.y = acc.y * n + bv.y;
        acc.z = acc.z * n + bv.z;
        acc.w = acc.w * n + bv.w;
        *(float4*)(out + (size_t)wid * 64 + lane * 4) = acc;
    }
}

// ---------------------------------------------------------------------------
extern "C" void kernel_launch(void* const* d_in, const int* in_sizes, int n_in,
                              void* d_out, int out_size, void* d_ws, size_t ws_size,
                              hipStream_t stream)
{
    const float* x  = (const float*)d_in[0];
    const float* W1 = (const float*)d_in[1];
    const float* b1 = (const float*)d_in[2];
    const float* W2 = (const float*)d_in[3];
    const float* b2 = (const float*)d_in[4];
    const float* W3 = (const float*)d_in[5];
    const float* b3 = (const float*)d_in[6];
    const int*  src = (const int*)d_in[7];
    const int*  dst = (const int*)d_in[8];

    const int E = in_sizes[7];
    const int N = in_sizes[0] / DIM;
    const int epg = E / NG;
    const int npg = N / NG;
    const int chunk = epg / CPG;

    // ws: ns[N] | nd[N] | hA[N*64 h] | hB[N*64 h] | rowptr[N+1] | cursor[N]
    //     | ssrc[E] | hsub[HISTB*npg] | dsub[HISTB*npg]   (~26 MB, no aliasing)
    float*  ns     = (float*)d_ws;
    float*  nd     = ns + N;
    __half* hA     = (__half*)(nd + N);
    __half* hB     = hA + (size_t)N * DIM;
    int*    rowptr = (int*)(hB + (size_t)N * DIM);
    int*    cursor = rowptr + N + 1;
    int*    ssrc   = cursor + N;
    int*    hsub   = ssrc + E;
    int*    dsub   = hsub + (size_t)HISTB * npg;
    float*  agg    = (float*)d_out;

    const int swiz = (N == 65536 && npg == 4096) ? 1 : 0;

    k1_hist_gemm<<<HISTB + N / 32, 256, 0, stream>>>(
        src, dst, hsub, dsub, chunk, npg, x, W1, hA, swiz);
    k2_scan<<<NG, 1024, 0, stream>>>(
        hsub, dsub, ns, nd, rowptr, cursor, epg, npg, N, E);
    k3_fill<<<256, 256, 0, stream>>>(src, dst, cursor, ssrc, E / 256);

    gg_kernel<<<N / GGN, 256, 0, stream>>>(
        hA, ssrc, rowptr, ns, nd, b1, W2, hB, N, 1, swiz);
    gg_kernel<<<N / GGN, 256, 0, stream>>>(
        hB, ssrc, rowptr, ns, nd, b2, W3, hA, N, 0, swiz);
    gather_kernel<<<N / 4, 256, 0, stream>>>(
        hA, ssrc, rowptr, agg, nd, b3, N, swiz);
}

// Round 2
// 258.849 us; speedup vs baseline: 1.1617x; 1.1617x over previous
//
#include <hip/hip_runtime.h>
#include <hip/hip_fp16.h>

#define DIM 64
#define NG  16          // num graphs
#define CPG 16          // edge chunks per graph (hist/fill parallelism)
#define NPG 4096        // nodes per graph
#define LSTR 68
#define HISTB (NG*CPG)  // 256 hist/fill blocks -> full CU coverage
#define GGN 32          // dst nodes per fused gather+gemm block

// ---------------------------------------------------------------------------
// K1: fused. Blocks [0,HISTB): per-chunk LDS degree histograms.
// Blocks [HISTB, HISTB+N/32): h16 = fp16(x @ W1) -- NO ns scaling (deferred
// to the gather as a per-edge multiply) so the GEMM is independent of the
// histogram and both run in one dispatch.
// ---------------------------------------------------------------------------
__global__ __launch_bounds__(256) void k1_hist_gemm(
    const int* __restrict__ src, const int* __restrict__ dst,
    int* __restrict__ hsub, int* __restrict__ dsub, int chunk, int npg,
    const float* __restrict__ x, const float* __restrict__ W1,
    __half* __restrict__ hout, int swiz)
{
    __shared__ int smem[8192];      // 32 KB union: hist(32KB) / gemm(26KB)
    const int tid = threadIdx.x;
    if ((int)blockIdx.x < HISTB) {
        int* hs = smem;
        int* hd = smem + NPG;
        const int blk = blockIdx.x;
        const int g = blk / CPG;
        const int ebase = blk * chunk;
        const int nbase = g * npg;
        for (int i = tid; i < npg; i += 256) { hs[i] = 0; hd[i] = 0; }
        __syncthreads();
        for (int e = tid; e < chunk; e += 256) {
            atomicAdd(&hs[src[ebase + e] - nbase], 1);
            atomicAdd(&hd[dst[ebase + e] - nbase], 1);
        }
        __syncthreads();
        for (int i = tid; i < npg; i += 256) {
            hsub[blk * npg + i] = hs[i];
            dsub[blk * npg + i] = hd[i];
        }
    } else {
        float* Wt = (float*)smem;            // Wt[c][k], 64*LSTR
        float* xs = Wt + 64 * LSTR;          // xs[r][k], 32*LSTR
        int blk = blockIdx.x - HISTB;
        if (swiz) {                          // 2048 blocks: 16 graphs x 128
            int xg = blk & 7;
            int j = blk >> 3;
            int g = xg + ((j >> 7) << 3);
            blk = (g << 7) + (j & 127);
        }
        const int row0 = blk * 32;
        for (int i = tid; i < 64 * 64; i += 256) {
            int k = i >> 6, c = i & 63;
            Wt[c * LSTR + k] = W1[i];
        }
        for (int i = tid; i < 32 * 64; i += 256) {
            int r = i >> 6, c = i & 63;
            xs[r * LSTR + c] = x[(size_t)(row0 + r) * 64 + c];
        }
        __syncthreads();
        const int c0 = tid & 31;
        const int r0 = tid >> 5;
        float acc[4][2] = {};
#pragma unroll
        for (int k = 0; k < 64; k += 4) {
            float4 w0 = *(const float4*)&Wt[(c0     ) * LSTR + k];
            float4 w1 = *(const float4*)&Wt[(c0 + 32) * LSTR + k];
#pragma unroll
            for (int rr = 0; rr < 4; ++rr) {
                float4 xv = *(const float4*)&xs[(r0 + 8 * rr) * LSTR + k];
                acc[rr][0] += xv.x * w0.x + xv.y * w0.y + xv.z * w0.z + xv.w * w0.w;
                acc[rr][1] += xv.x * w1.x + xv.y * w1.y + xv.z * w1.z + xv.w * w1.w;
            }
        }
#pragma unroll
        for (int rr = 0; rr < 4; ++rr) {
            int row = row0 + r0 + 8 * rr;
            hout[(size_t)row * 64 + c0     ] = __float2half_rn(acc[rr][0]);
            hout[(size_t)row * 64 + c0 + 32] = __float2half_rn(acc[rr][1]);
        }
    }
}

// ---------------------------------------------------------------------------
// K2: one block per graph.
//  Phase A: coalesced sum of sub-hists -> ns/nd, dst degrees in LDS.
//  Phase B: shuffle-based exclusive scan -> rowptr; node starts into LDS.
//  Phase C: rewrite dsub in-place to per-chunk ABSOLUTE cursor starts
//           (stable counting sort; consumed by K3's LDS cursors).
// ---------------------------------------------------------------------------
__global__ __launch_bounds__(1024) void k2_scan(
    const int* __restrict__ hsub, int* __restrict__ dsub,
    float* __restrict__ ns, float* __restrict__ nd,
    int* __restrict__ rowptr, int epg, int npg, int N, int E)
{
    __shared__ int ddeg[NPG];       // 16 KB: degrees, then starts
    __shared__ int wsum[16];
    const int g = blockIdx.x;
    const int t = threadIdx.x;
    const int nbase = g * npg;
    const int ebase = g * epg;
    // Phase A: fully coalesced sweep (i = t + r*1024)
    for (int i = t; i < npg; i += 1024) {
        int sd = 0, dd = 0;
#pragma unroll
        for (int k = 0; k < CPG; ++k) {
            sd += hsub[(g * CPG + k) * npg + i];
            dd += dsub[(g * CPG + k) * npg + i];
        }
        ns[nbase + i] = sd > 0 ? rsqrtf((float)sd) : 0.0f;
        nd[nbase + i] = dd > 0 ? rsqrtf((float)dd) : 0.0f;
        ddeg[i] = dd;
    }
    __syncthreads();
    // Phase B: thread t owns rows 4t..4t+3; shuffle scan over 1024 threads
    const int i0 = 4 * t;
    int d0 = ddeg[i0], d1 = ddeg[i0 + 1], d2 = ddeg[i0 + 2], d3 = ddeg[i0 + 3];
    int s4 = d0 + d1 + d2 + d3;
    const int lane = t & 63, wid = t >> 6;
    int v = s4;
#pragma unroll
    for (int off = 1; off < 64; off <<= 1) {
        int u = __shfl_up(v, off, 64);
        if (lane >= off) v += u;
    }
    if (lane == 63) wsum[wid] = v;
    __syncthreads();
    if (t < 16) {
        int w = wsum[t];
#pragma unroll
        for (int off = 1; off < 16; off <<= 1) {
            int u = __shfl_up(w, off, 16);
            if (t >= off) w += u;
        }
        wsum[t] = w;    // inclusive wave sums
    }
    __syncthreads();
    int incl = v + (wid > 0 ? wsum[wid - 1] : 0);
    int c = ebase + incl - s4;      // exclusive prefix for row i0
    rowptr[nbase + i0    ] = c; ddeg[i0    ] = c; c += d0;
    rowptr[nbase + i0 + 1] = c; ddeg[i0 + 1] = c; c += d1;
    rowptr[nbase + i0 + 2] = c; ddeg[i0 + 2] = c; c += d2;
    rowptr[nbase + i0 + 3] = c; ddeg[i0 + 3] = c;
    if (g == 0 && t == 0) rowptr[N] = E;
    __syncthreads();
    // Phase C: coalesced in-place prefix over chunks -> absolute starts
    for (int i = t; i < npg; i += 1024) {
        int cc = ddeg[i];
#pragma unroll
        for (int k = 0; k < CPG; ++k) {
            int* p = &dsub[(g * CPG + k) * npg + i];
            int old = *p; *p = cc; cc += old;
        }
    }
}

// ---------------------------------------------------------------------------
// K3: fill ssrc. LDS cursors init from per-chunk absolute starts.
// No global atomics (the 74us lesson: global cursor atomics serialize at L2).
// ---------------------------------------------------------------------------
__global__ __launch_bounds__(256) void k3_fill(
    const int* __restrict__ src, const int* __restrict__ dst,
    const int* __restrict__ dsub, int* __restrict__ ssrc, int chunk, int npg)
{
    __shared__ int cur[NPG];
    const int blk = blockIdx.x;
    const int g = blk / CPG;
    const int t = threadIdx.x;
    const int ebase = blk * chunk;
    const int nbase = g * npg;
    for (int i = t; i < npg; i += 256) cur[i] = dsub[blk * npg + i];
    __syncthreads();
    for (int e = t; e < chunk; e += 256) {
        int s = src[ebase + e];
        int d = dst[ebase + e] - nbase;
        int pos = atomicAdd(&cur[d], 1);
        ssrc[pos] = s;
    }
}

// ---------------------------------------------------------------------------
// Fused gather + next-layer GEMM. Per dst node w:
//   acc = sum_{e in(w)} [ns[s] *] h[s]      (nsfold only for layer-1 output)
//   u   = acc * (nd[w]*ns[w]) + ns[w]*bprev  (prev epilogue + next pre-scale)
//   y   = u @ W ;  hout[w] = fp16(y)
// Block: 4 waves x 8 nodes = 32 nodes. W staged in LDS once per block.
// ---------------------------------------------------------------------------
__device__ __forceinline__ void acc_h4(float4& acc, uint2 u)
{
    __half2 p = *(__half2*)&u.x;
    __half2 q = *(__half2*)&u.y;
    float2 f0 = __half22float2(p);
    float2 f1 = __half22float2(q);
    acc.x += f0.x; acc.y += f0.y; acc.z += f1.x; acc.w += f1.y;
}

__device__ __forceinline__ void acc_h4s(float4& acc, uint2 u, float s)
{
    __half2 p = *(__half2*)&u.x;
    __half2 q = *(__half2*)&u.y;
    float2 f0 = __half22float2(p);
    float2 f1 = __half22float2(q);
    acc.x += s * f0.x; acc.y += s * f0.y; acc.z += s * f1.x; acc.w += s * f1.y;
}

__global__ __launch_bounds__(256) void gg_kernel(
    const __half* __restrict__ h, const int* __restrict__ ssrc,
    const int* __restrict__ rowptr, const float* __restrict__ ns,
    const float* __restrict__ nd, const float* __restrict__ bprev,
    const float* __restrict__ W, __half* __restrict__ hout,
    int N, int nsfold, int swiz)
{
    __shared__ float Ws[64 * 64];        // W[k][c] row-major, 16 KB
    __shared__ float us[GGN][64];        // scaled agg rows, 8 KB
    int blk = blockIdx.x;
    if (swiz) {                          // 2048 blocks: 16 graphs x 128
        int xg = blk & 7;
        int j = blk >> 3;
        int g = xg + ((j >> 7) << 3);
        blk = (g << 7) + (j & 127);
    }
    const int tid = threadIdx.x;
    for (int i = tid; i < 64 * 64; i += 256) Ws[i] = W[i];

    const int wv = tid >> 6;
    const int lane = tid & 63;
    const int grp = lane >> 4;
    const int sub = lane & 15;
    const int node0 = blk * GGN + wv * 8;

    for (int n = 0; n < 8; ++n) {
        int w = node0 + n;
        if (w >= N) break;
        int beg = rowptr[w], end = rowptr[w + 1];
        float4 acc = {0.f, 0.f, 0.f, 0.f};
        int j = beg + grp;
        if (nsfold) {
            for (; j + 12 < end; j += 16) {
                int s0 = ssrc[j];
                int s1 = ssrc[j + 4];
                int s2 = ssrc[j + 8];
                int s3 = ssrc[j + 12];
                float n0 = ns[s0], n1 = ns[s1], n2 = ns[s2], n3 = ns[s3];
                uint2 u0 = *(const uint2*)(h + (size_t)s0 * 64 + sub * 4);
                uint2 u1 = *(const uint2*)(h + (size_t)s1 * 64 + sub * 4);
                uint2 u2 = *(const uint2*)(h + (size_t)s2 * 64 + sub * 4);
                uint2 u3 = *(const uint2*)(h + (size_t)s3 * 64 + sub * 4);
                acc_h4s(acc, u0, n0); acc_h4s(acc, u1, n1);
                acc_h4s(acc, u2, n2); acc_h4s(acc, u3, n3);
            }
            for (; j < end; j += 4) {
                int s = ssrc[j];
                float nn = ns[s];
                uint2 u = *(const uint2*)(h + (size_t)s * 64 + sub * 4);
                acc_h4s(acc, u, nn);
            }
        } else {
            for (; j + 12 < end; j += 16) {
                int s0 = ssrc[j];
                int s1 = ssrc[j + 4];
                int s2 = ssrc[j + 8];
                int s3 = ssrc[j + 12];
                uint2 u0 = *(const uint2*)(h + (size_t)s0 * 64 + sub * 4);
                uint2 u1 = *(const uint2*)(h + (size_t)s1 * 64 + sub * 4);
                uint2 u2 = *(const uint2*)(h + (size_t)s2 * 64 + sub * 4);
                uint2 u3 = *(const uint2*)(h + (size_t)s3 * 64 + sub * 4);
                acc_h4(acc, u0); acc_h4(acc, u1); acc_h4(acc, u2); acc_h4(acc, u3);
            }
            for (; j < end; j += 4) {
                int s = ssrc[j];
                uint2 u = *(const uint2*)(h + (size_t)s * 64 + sub * 4);
                acc_h4(acc, u);
            }
        }
#pragma unroll
        for (int off = 32; off >= 16; off >>= 1) {
            acc.x += __shfl_down(acc.x, off, 64);
            acc.y += __shfl_down(acc.y, off, 64);
            acc.z += __shfl_down(acc.z, off, 64);
            acc.w += __shfl_down(acc.w, off, 64);
        }
        if (lane < 16) {
            float sw = ns[w];
            float alpha = nd[w] * sw;
            float4 bv = *(const float4*)(bprev + lane * 4);
            float4 uo;
            uo.x = acc.x * alpha + sw * bv.x;
            uo.y = acc.y * alpha + sw * bv.y;
            uo.z = acc.z * alpha + sw * bv.z;
            uo.w = acc.w * alpha + sw * bv.w;
            *(float4*)&us[wv * 8 + n][lane * 4] = uo;
        }
    }
    __syncthreads();
    // Epilogue GEMM: thread -> (node nl, col c). us read is wave-uniform
    // (broadcast); Ws[k*64+c] is stride-1 across lanes (2-way alias, free).
    const int c = tid & 63;
#pragma unroll
    for (int m = 0; m < 8; ++m) {
        int nl = (tid >> 6) + 4 * m;
        int w = blk * GGN + nl;
        if (w >= N) continue;
        const float* ur = us[nl];
        float y = 0.f;
#pragma unroll
        for (int k = 0; k < 64; k += 4) {
            float4 uv = *(const float4*)&ur[k];
            y += uv.x * Ws[(k    ) * 64 + c]
               + uv.y * Ws[(k + 1) * 64 + c]
               + uv.z * Ws[(k + 2) * 64 + c]
               + uv.w * Ws[(k + 3) * 64 + c];
        }
        hout[(size_t)w * 64 + c] = __float2half_rn(y);
    }
}

// ---------------------------------------------------------------------------
// Final gather (layer 3): acc*nd + b3 -> fp32 out.
// ---------------------------------------------------------------------------
__global__ __launch_bounds__(256) void gather_kernel(
    const __half* __restrict__ h, const int* __restrict__ ssrc,
    const int* __restrict__ rowptr, float* __restrict__ out,
    const float* __restrict__ nd, const float* __restrict__ b,
    int N, int swiz)
{
    int blk = blockIdx.x;
    if (swiz) {                        // 16384 blocks: 16 graphs x 1024
        int x = blk & 7;
        int j = blk >> 3;
        int g = x + ((j >> 10) << 3);
        blk = (g << 10) + (j & 1023);
    }
    int wid  = blk * 4 + (threadIdx.x >> 6);
    int lane = threadIdx.x & 63;
    if (wid >= N) return;
    int beg = rowptr[wid], end = rowptr[wid + 1];
    int grp = lane >> 4;
    int sub = lane & 15;
    float4 acc = {0.f, 0.f, 0.f, 0.f};
    int j = beg + grp;
    for (; j + 12 < end; j += 16) {
        int s0 = ssrc[j];
        int s1 = ssrc[j + 4];
        int s2 = ssrc[j + 8];
        int s3 = ssrc[j + 12];
        uint2 u0 = *(const uint2*)(h + (size_t)s0 * 64 + sub * 4);
        uint2 u1 = *(const uint2*)(h + (size_t)s1 * 64 + sub * 4);
        uint2 u2 = *(const uint2*)(h + (size_t)s2 * 64 + sub * 4);
        uint2 u3 = *(const uint2*)(h + (size_t)s3 * 64 + sub * 4);
        acc_h4(acc, u0); acc_h4(acc, u1); acc_h4(acc, u2); acc_h4(acc, u3);
    }
    for (; j < end; j += 4) {
        int s = ssrc[j];
        uint2 u = *(const uint2*)(h + (size_t)s * 64 + sub * 4);
        acc_h4(acc, u);
    }
#pragma unroll
    for (int off = 32; off >= 16; off >>= 1) {
        acc.x += __shfl_down(acc.x, off, 64);
        acc.y += __shfl_down(acc.y, off, 64);
        acc.z += __shfl_down(acc.z, off, 64);
        acc.w += __shfl_down(acc.w, off, 64);
    }
    if (lane < 16) {
        float n = nd[wid];
        const float4 bv = *(const float4*)(b + lane * 4);
        acc.x = acc.x * n + bv.x;
        acc.y = acc.y * n + bv.y;
        acc.z = acc.z * n + bv.z;
        acc.w = acc.w * n + bv.w;
        *(float4*)(out + (size_t)wid * 64 + lane * 4) = acc;
    }
}

// ---------------------------------------------------------------------------
extern "C" void kernel_launch(void* const* d_in, const int* in_sizes, int n_in,
                              void* d_out, int out_size, void* d_ws, size_t ws_size,
                              hipStream_t stream)
{
    const float* x  = (const float*)d_in[0];
    const float* W1 = (const float*)d_in[1];
    const float* b1 = (const float*)d_in[2];
    const float* W2 = (const float*)d_in[3];
    const float* b2 = (const float*)d_in[4];
    const float* W3 = (const float*)d_in[5];
    const float* b3 = (const float*)d_in[6];
    const int*  src = (const int*)d_in[7];
    const int*  dst = (const int*)d_in[8];

    const int E = in_sizes[7];
    const int N = in_sizes[0] / DIM;
    const int epg = E / NG;
    const int npg = N / NG;
    const int chunk = epg / CPG;

    // ws: ns[N] | nd[N] | hA[N*64 h] | hB[N*64 h] | rowptr[N+1] | ssrc[E]
    //     | hsub[HISTB*npg] | dsub[HISTB*npg]   (~30 MB, no aliasing)
    float*  ns     = (float*)d_ws;
    float*  nd     = ns + N;
    __half* hA     = (__half*)(nd + N);
    __half* hB     = hA + (size_t)N * DIM;
    int*    rowptr = (int*)(hB + (size_t)N * DIM);
    int*    ssrc   = rowptr + N + 1;
    int*    hsub   = ssrc + E;
    int*    dsub   = hsub + (size_t)HISTB * npg;
    float*  agg    = (float*)d_out;

    const int swiz = (N == 65536 && npg == 4096) ? 1 : 0;

    k1_hist_gemm<<<HISTB + N / 32, 256, 0, stream>>>(
        src, dst, hsub, dsub, chunk, npg, x, W1, hA, swiz);
    k2_scan<<<NG, 1024, 0, stream>>>(
        hsub, dsub, ns, nd, rowptr, epg, npg, N, E);
    k3_fill<<<HISTB, 256, 0, stream>>>(src, dst, dsub, ssrc, chunk, npg);

    gg_kernel<<<N / GGN, 256, 0, stream>>>(
        hA, ssrc, rowptr, ns, nd, b1, W2, hB, N, 1, swiz);
    gg_kernel<<<N / GGN, 256, 0, stream>>>(
        hB, ssrc, rowptr, ns, nd, b2, W3, hA, N, 0, swiz);
    gather_kernel<<<N / 4, 256, 0, stream>>>(
        hA, ssrc, rowptr, agg, nd, b3, N, swiz);
}

// Round 3
// 237.240 us; speedup vs baseline: 1.2675x; 1.0911x over previous
//
#include <hip/hip_runtime.h>
#include <hip/hip_fp16.h>

#define DIM 64
#define NG  16          // num graphs
#define CPG 16          // edge chunks per graph (hist/fill parallelism)
#define NPG 4096        // nodes per graph
#define LSTR 68
#define HISTB (NG*CPG)  // 256 hist/fill blocks -> full CU coverage
#define GGN 32          // dst nodes per fused gather+gemm block

// ---------------------------------------------------------------------------
// K1: fused. Blocks [0,HISTB): per-chunk LDS degree histograms.
// Blocks [HISTB, HISTB+N/32): h16 = fp16(x @ W1) -- NO ns scaling (deferred
// to the gather as a per-edge multiply) so the GEMM is independent of the
// histogram and both run in one dispatch.
// ---------------------------------------------------------------------------
__global__ __launch_bounds__(256) void k1_hist_gemm(
    const int* __restrict__ src, const int* __restrict__ dst,
    int* __restrict__ hsub, int* __restrict__ dsub, int chunk, int npg,
    const float* __restrict__ x, const float* __restrict__ W1,
    __half* __restrict__ hout, int swiz)
{
    __shared__ int smem[8192];      // 32 KB union: hist(32KB) / gemm(26KB)
    const int tid = threadIdx.x;
    if ((int)blockIdx.x < HISTB) {
        int* hs = smem;
        int* hd = smem + NPG;
        const int blk = blockIdx.x;
        const int g = blk / CPG;
        const int ebase = blk * chunk;
        const int nbase = g * npg;
        for (int i = tid; i < npg; i += 256) { hs[i] = 0; hd[i] = 0; }
        __syncthreads();
        for (int e = tid; e < chunk; e += 256) {
            atomicAdd(&hs[src[ebase + e] - nbase], 1);
            atomicAdd(&hd[dst[ebase + e] - nbase], 1);
        }
        __syncthreads();
        for (int i = tid; i < npg; i += 256) {
            hsub[blk * npg + i] = hs[i];
            dsub[blk * npg + i] = hd[i];
        }
    } else {
        float* Wt = (float*)smem;            // Wt[c][k], 64*LSTR
        float* xs = Wt + 64 * LSTR;          // xs[r][k], 32*LSTR
        int blk = blockIdx.x - HISTB;
        if (swiz) {                          // 2048 blocks: 16 graphs x 128
            int xg = blk & 7;
            int j = blk >> 3;
            int g = xg + ((j >> 7) << 3);
            blk = (g << 7) + (j & 127);
        }
        const int row0 = blk * 32;
        for (int i = tid; i < 64 * 64; i += 256) {
            int k = i >> 6, c = i & 63;
            Wt[c * LSTR + k] = W1[i];
        }
        for (int i = tid; i < 32 * 64; i += 256) {
            int r = i >> 6, c = i & 63;
            xs[r * LSTR + c] = x[(size_t)(row0 + r) * 64 + c];
        }
        __syncthreads();
        const int c0 = tid & 31;
        const int r0 = tid >> 5;
        float acc[4][2] = {};
#pragma unroll
        for (int k = 0; k < 64; k += 4) {
            float4 w0 = *(const float4*)&Wt[(c0     ) * LSTR + k];
            float4 w1 = *(const float4*)&Wt[(c0 + 32) * LSTR + k];
#pragma unroll
            for (int rr = 0; rr < 4; ++rr) {
                float4 xv = *(const float4*)&xs[(r0 + 8 * rr) * LSTR + k];
                acc[rr][0] += xv.x * w0.x + xv.y * w0.y + xv.z * w0.z + xv.w * w0.w;
                acc[rr][1] += xv.x * w1.x + xv.y * w1.y + xv.z * w1.z + xv.w * w1.w;
            }
        }
#pragma unroll
        for (int rr = 0; rr < 4; ++rr) {
            int row = row0 + r0 + 8 * rr;
            hout[(size_t)row * 64 + c0     ] = __float2half_rn(acc[rr][0]);
            hout[(size_t)row * 64 + c0 + 32] = __float2half_rn(acc[rr][1]);
        }
    }
}

// ---------------------------------------------------------------------------
// K2: one block per graph.
//  Phase A: coalesced sum of sub-hists -> ns/nd, dst degrees in LDS.
//  Phase B: shuffle-based exclusive scan -> rowptr; node starts into LDS.
//  Phase C: rewrite dsub in-place to per-chunk ABSOLUTE cursor starts
//           (stable counting sort; consumed by K3's LDS cursors).
// ---------------------------------------------------------------------------
__global__ __launch_bounds__(1024) void k2_scan(
    const int* __restrict__ hsub, int* __restrict__ dsub,
    float* __restrict__ ns, float* __restrict__ nd,
    int* __restrict__ rowptr, int epg, int npg, int N, int E)
{
    __shared__ int ddeg[NPG];       // 16 KB: degrees, then starts
    __shared__ int wsum[16];
    const int g = blockIdx.x;
    const int t = threadIdx.x;
    const int nbase = g * npg;
    const int ebase = g * epg;
    // Phase A: fully coalesced sweep (i = t + r*1024)
    for (int i = t; i < npg; i += 1024) {
        int sd = 0, dd = 0;
#pragma unroll
        for (int k = 0; k < CPG; ++k) {
            sd += hsub[(g * CPG + k) * npg + i];
            dd += dsub[(g * CPG + k) * npg + i];
        }
        ns[nbase + i] = sd > 0 ? rsqrtf((float)sd) : 0.0f;
        nd[nbase + i] = dd > 0 ? rsqrtf((float)dd) : 0.0f;
        ddeg[i] = dd;
    }
    __syncthreads();
    // Phase B: thread t owns rows 4t..4t+3; shuffle scan over 1024 threads
    const int i0 = 4 * t;
    int d0 = ddeg[i0], d1 = ddeg[i0 + 1], d2 = ddeg[i0 + 2], d3 = ddeg[i0 + 3];
    int s4 = d0 + d1 + d2 + d3;
    const int lane = t & 63, wid = t >> 6;
    int v = s4;
#pragma unroll
    for (int off = 1; off < 64; off <<= 1) {
        int u = __shfl_up(v, off, 64);
        if (lane >= off) v += u;
    }
    if (lane == 63) wsum[wid] = v;
    __syncthreads();
    if (t < 16) {
        int w = wsum[t];
#pragma unroll
        for (int off = 1; off < 16; off <<= 1) {
            int u = __shfl_up(w, off, 16);
            if (t >= off) w += u;
        }
        wsum[t] = w;    // inclusive wave sums
    }
    __syncthreads();
    int incl = v + (wid > 0 ? wsum[wid - 1] : 0);
    int c = ebase + incl - s4;      // exclusive prefix for row i0
    rowptr[nbase + i0    ] = c; ddeg[i0    ] = c; c += d0;
    rowptr[nbase + i0 + 1] = c; ddeg[i0 + 1] = c; c += d1;
    rowptr[nbase + i0 + 2] = c; ddeg[i0 + 2] = c; c += d2;
    rowptr[nbase + i0 + 3] = c; ddeg[i0 + 3] = c;
    if (g == 0 && t == 0) rowptr[N] = E;
    __syncthreads();
    // Phase C: coalesced in-place prefix over chunks -> absolute starts
    for (int i = t; i < npg; i += 1024) {
        int cc = ddeg[i];
#pragma unroll
        for (int k = 0; k < CPG; ++k) {
            int* p = &dsub[(g * CPG + k) * npg + i];
            int old = *p; *p = cc; cc += old;
        }
    }
}

// ---------------------------------------------------------------------------
// K3: fill ssrc. LDS cursors init from per-chunk absolute starts.
// No global atomics (the 74us lesson: global cursor atomics serialize at L2).
// ---------------------------------------------------------------------------
__global__ __launch_bounds__(256) void k3_fill(
    const int* __restrict__ src, const int* __restrict__ dst,
    const int* __restrict__ dsub, int* __restrict__ ssrc, int chunk, int npg)
{
    __shared__ int cur[NPG];
    const int blk = blockIdx.x;
    const int g = blk / CPG;
    const int t = threadIdx.x;
    const int ebase = blk * chunk;
    const int nbase = g * npg;
    for (int i = t; i < npg; i += 256) cur[i] = dsub[blk * npg + i];
    __syncthreads();
    for (int e = t; e < chunk; e += 256) {
        int s = src[ebase + e];
        int d = dst[ebase + e] - nbase;
        int pos = atomicAdd(&cur[d], 1);
        ssrc[pos] = s;
    }
}

// ---------------------------------------------------------------------------
// Gather core, group-per-node: 16 lanes own ALL 64 dims of one node (lane
// sub = dims 4*sub..4*sub+3). No cross-lane reduce. ILP-8 main loop (32
// independent 512B loads in flight per wave) + one branch-free predicated
// tail (clamped index, zero scale) -- no serial 1-edge cleanup loop.
// ---------------------------------------------------------------------------
__device__ __forceinline__ void acc_h4(float4& acc, uint2 u)
{
    __half2 p = *(__half2*)&u.x;
    __half2 q = *(__half2*)&u.y;
    float2 f0 = __half22float2(p);
    float2 f1 = __half22float2(q);
    acc.x += f0.x; acc.y += f0.y; acc.z += f1.x; acc.w += f1.y;
}

__device__ __forceinline__ void acc_h4s(float4& acc, uint2 u, float s)
{
    __half2 p = *(__half2*)&u.x;
    __half2 q = *(__half2*)&u.y;
    float2 f0 = __half22float2(p);
    float2 f1 = __half22float2(q);
    acc.x += s * f0.x; acc.y += s * f0.y; acc.z += s * f1.x; acc.w += s * f1.y;
}

__device__ __forceinline__ float4 gather_node(
    const __half* __restrict__ h, const int* __restrict__ ssrc,
    const float* __restrict__ ns, int beg, int end, int sub, int nsfold)
{
    float4 acc = {0.f, 0.f, 0.f, 0.f};
    int j = beg;
    if (nsfold) {
        for (; j + 7 < end; j += 8) {
            int s0 = ssrc[j+0], s1 = ssrc[j+1], s2 = ssrc[j+2], s3 = ssrc[j+3];
            int s4 = ssrc[j+4], s5 = ssrc[j+5], s6 = ssrc[j+6], s7 = ssrc[j+7];
            float n0 = ns[s0], n1 = ns[s1], n2 = ns[s2], n3 = ns[s3];
            float n4 = ns[s4], n5 = ns[s5], n6 = ns[s6], n7 = ns[s7];
            uint2 u0 = *(const uint2*)(h + (size_t)s0 * 64 + sub * 4);
            uint2 u1 = *(const uint2*)(h + (size_t)s1 * 64 + sub * 4);
            uint2 u2 = *(const uint2*)(h + (size_t)s2 * 64 + sub * 4);
            uint2 u3 = *(const uint2*)(h + (size_t)s3 * 64 + sub * 4);
            uint2 u4 = *(const uint2*)(h + (size_t)s4 * 64 + sub * 4);
            uint2 u5 = *(const uint2*)(h + (size_t)s5 * 64 + sub * 4);
            uint2 u6 = *(const uint2*)(h + (size_t)s6 * 64 + sub * 4);
            uint2 u7 = *(const uint2*)(h + (size_t)s7 * 64 + sub * 4);
            acc_h4s(acc, u0, n0); acc_h4s(acc, u1, n1);
            acc_h4s(acc, u2, n2); acc_h4s(acc, u3, n3);
            acc_h4s(acc, u4, n4); acc_h4s(acc, u5, n5);
            acc_h4s(acc, u6, n6); acc_h4s(acc, u7, n7);
        }
    } else {
        for (; j + 7 < end; j += 8) {
            int s0 = ssrc[j+0], s1 = ssrc[j+1], s2 = ssrc[j+2], s3 = ssrc[j+3];
            int s4 = ssrc[j+4], s5 = ssrc[j+5], s6 = ssrc[j+6], s7 = ssrc[j+7];
            uint2 u0 = *(const uint2*)(h + (size_t)s0 * 64 + sub * 4);
            uint2 u1 = *(const uint2*)(h + (size_t)s1 * 64 + sub * 4);
            uint2 u2 = *(const uint2*)(h + (size_t)s2 * 64 + sub * 4);
            uint2 u3 = *(const uint2*)(h + (size_t)s3 * 64 + sub * 4);
            uint2 u4 = *(const uint2*)(h + (size_t)s4 * 64 + sub * 4);
            uint2 u5 = *(const uint2*)(h + (size_t)s5 * 64 + sub * 4);
            uint2 u6 = *(const uint2*)(h + (size_t)s6 * 64 + sub * 4);
            uint2 u7 = *(const uint2*)(h + (size_t)s7 * 64 + sub * 4);
            acc_h4(acc, u0); acc_h4(acc, u1); acc_h4(acc, u2); acc_h4(acc, u3);
            acc_h4(acc, u4); acc_h4(acc, u5); acc_h4(acc, u6); acc_h4(acc, u7);
        }
    }
    int rem = end - j;
    if (rem > 0) {
#pragma unroll
        for (int q = 0; q < 4; ++q) {
            int jj = j + (q < rem ? q : rem - 1);    // clamped: always valid
            int s = ssrc[jj];
            uint2 u = *(const uint2*)(h + (size_t)s * 64 + sub * 4);
            float sc = (q < rem) ? (nsfold ? ns[s] : 1.0f) : 0.0f;
            acc_h4s(acc, u, sc);
        }
    }
    if (rem > 4) {
#pragma unroll
        for (int q = 4; q < 8; ++q) {
            int jj = j + (q < rem ? q : rem - 1);
            int s = ssrc[jj];
            uint2 u = *(const uint2*)(h + (size_t)s * 64 + sub * 4);
            float sc = (q < rem) ? (nsfold ? ns[s] : 1.0f) : 0.0f;
            acc_h4s(acc, u, sc);
        }
    }
    return acc;
}

// ---------------------------------------------------------------------------
// Fused gather + next-layer GEMM. Per dst node w:
//   acc = sum_{e in(w)} [ns[s] *] h[s]      (nsfold only for layer-1 output)
//   u   = acc * (nd[w]*ns[w]) + ns[w]*bprev  (prev epilogue + next pre-scale)
//   y   = u @ W ;  hout[w] = fp16(y)
// Block: 4 waves x 4 node-groups x 2 passes = 32 nodes. No shuffle reduce.
// ---------------------------------------------------------------------------
__global__ __launch_bounds__(256) void gg_kernel(
    const __half* __restrict__ h, const int* __restrict__ ssrc,
    const int* __restrict__ rowptr, const float* __restrict__ ns,
    const float* __restrict__ nd, const float* __restrict__ bprev,
    const float* __restrict__ W, __half* __restrict__ hout,
    int N, int nsfold, int swiz)
{
    __shared__ float Ws[64 * 64];        // W[k][c] row-major, 16 KB
    __shared__ float us[GGN][64];        // scaled agg rows, 8 KB
    int blk = blockIdx.x;
    if (swiz) {                          // 2048 blocks: 16 graphs x 128
        int xg = blk & 7;
        int j = blk >> 3;
        int g = xg + ((j >> 7) << 3);
        blk = (g << 7) + (j & 127);
    }
    const int tid = threadIdx.x;
    for (int i = tid; i < 64 * 64; i += 256) Ws[i] = W[i];

    const int wv = tid >> 6;
    const int lane = tid & 63;
    const int grp = lane >> 4;           // node slot within wave
    const int sub = lane & 15;           // dim quad

#pragma unroll
    for (int p = 0; p < GGN / 16; ++p) {
        int nl = p * 16 + wv * 4 + grp;
        int w = blk * GGN + nl;
        if (w < N) {
            int beg = rowptr[w], end = rowptr[w + 1];
            float4 acc = gather_node(h, ssrc, ns, beg, end, sub, nsfold);
            float sw = ns[w];
            float alpha = nd[w] * sw;
            float4 bv = *(const float4*)(bprev + sub * 4);
            float4 uo;
            uo.x = acc.x * alpha + sw * bv.x;
            uo.y = acc.y * alpha + sw * bv.y;
            uo.z = acc.z * alpha + sw * bv.z;
            uo.w = acc.w * alpha + sw * bv.w;
            *(float4*)&us[nl][sub * 4] = uo;
        }
    }
    __syncthreads();
    // Epilogue GEMM: thread -> (node nl, col c). us read is wave-uniform
    // (broadcast); Ws[k*64+c] is stride-1 across lanes (2-way alias, free).
    const int c = tid & 63;
#pragma unroll
    for (int m = 0; m < 8; ++m) {
        int nl = (tid >> 6) + 4 * m;
        int w = blk * GGN + nl;
        if (w >= N) continue;
        const float* ur = us[nl];
        float y = 0.f;
#pragma unroll
        for (int k = 0; k < 64; k += 4) {
            float4 uv = *(const float4*)&ur[k];
            y += uv.x * Ws[(k    ) * 64 + c]
               + uv.y * Ws[(k + 1) * 64 + c]
               + uv.z * Ws[(k + 2) * 64 + c]
               + uv.w * Ws[(k + 3) * 64 + c];
        }
        hout[(size_t)w * 64 + c] = __float2half_rn(y);
    }
}

// ---------------------------------------------------------------------------
// Final gather (layer 3): group-per-node, acc*nd + b3 -> fp32 out.
// 4 waves x 4 groups = 16 nodes/block.
// ---------------------------------------------------------------------------
__global__ __launch_bounds__(256) void gather_kernel(
    const __half* __restrict__ h, const int* __restrict__ ssrc,
    const int* __restrict__ rowptr, float* __restrict__ out,
    const float* __restrict__ nd, const float* __restrict__ b,
    int N, int swiz)
{
    int blk = blockIdx.x;
    if (swiz) {                        // 4096 blocks: 16 graphs x 256
        int x = blk & 7;
        int j = blk >> 3;
        int g = x + ((j >> 8) << 3);
        blk = (g << 8) + (j & 255);
    }
    const int wv = threadIdx.x >> 6;
    const int lane = threadIdx.x & 63;
    const int grp = lane >> 4;
    const int sub = lane & 15;
    int w = blk * 16 + wv * 4 + grp;
    if (w >= N) return;
    int beg = rowptr[w], end = rowptr[w + 1];
    float4 acc = gather_node(h, ssrc, (const float*)nullptr, beg, end, sub, 0);
    float n = nd[w];
    const float4 bv = *(const float4*)(b + sub * 4);
    acc.x = acc.x * n + bv.x;
    acc.y = acc.y * n + bv.y;
    acc.z = acc.z * n + bv.z;
    acc.w = acc.w * n + bv.w;
    *(float4*)(out + (size_t)w * 64 + sub * 4) = acc;
}

// ---------------------------------------------------------------------------
extern "C" void kernel_launch(void* const* d_in, const int* in_sizes, int n_in,
                              void* d_out, int out_size, void* d_ws, size_t ws_size,
                              hipStream_t stream)
{
    const float* x  = (const float*)d_in[0];
    const float* W1 = (const float*)d_in[1];
    const float* b1 = (const float*)d_in[2];
    const float* W2 = (const float*)d_in[3];
    const float* b2 = (const float*)d_in[4];
    const float* W3 = (const float*)d_in[5];
    const float* b3 = (const float*)d_in[6];
    const int*  src = (const int*)d_in[7];
    const int*  dst = (const int*)d_in[8];

    const int E = in_sizes[7];
    const int N = in_sizes[0] / DIM;
    const int epg = E / NG;
    const int npg = N / NG;
    const int chunk = epg / CPG;

    // ws: ns[N] | nd[N] | hA[N*64 h] | hB[N*64 h] | rowptr[N+1] | ssrc[E]
    //     | hsub[HISTB*npg] | dsub[HISTB*npg]   (~30 MB, no aliasing)
    float*  ns     = (float*)d_ws;
    float*  nd     = ns + N;
    __half* hA     = (__half*)(nd + N);
    __half* hB     = hA + (size_t)N * DIM;
    int*    rowptr = (int*)(hB + (size_t)N * DIM);
    int*    ssrc   = rowptr + N + 1;
    int*    hsub   = ssrc + E;
    int*    dsub   = hsub + (size_t)HISTB * npg;
    float*  agg    = (float*)d_out;

    const int swiz = (N == 65536 && npg == 4096) ? 1 : 0;

    k1_hist_gemm<<<HISTB + N / 32, 256, 0, stream>>>(
        src, dst, hsub, dsub, chunk, npg, x, W1, hA, swiz);
    k2_scan<<<NG, 1024, 0, stream>>>(
        hsub, dsub, ns, nd, rowptr, epg, npg, N, E);
    k3_fill<<<HISTB, 256, 0, stream>>>(src, dst, dsub, ssrc, chunk, npg);

    gg_kernel<<<N / GGN, 256, 0, stream>>>(
        hA, ssrc, rowptr, ns, nd, b1, W2, hB, N, 1, swiz);
    gg_kernel<<<N / GGN, 256, 0, stream>>>(
        hB, ssrc, rowptr, ns, nd, b2, W3, hA, N, 0, swiz);
    gather_kernel<<<N / 16, 256, 0, stream>>>(
        hA, ssrc, rowptr, agg, nd, b3, N, swiz);
}